// Round 8
// baseline (3290.299 us; speedup 1.0000x reference)
//
#include <hip/hip_runtime.h>
#include <hip/hip_bf16.h>

typedef __bf16 bf16_t;
typedef __bf16 bf16x8 __attribute__((ext_vector_type(8)));
typedef float f32x4 __attribute__((ext_vector_type(4)));

#define Bn 8
#define Tn 2048
#define Cn 2048
#define Hn 32
#define HSn 64
#define CT 64

static const long SZ = (long)Bn * Tn * Cn;   // 33,554,432 elements

__device__ __forceinline__ void g2l16(const void* g, void* l) {
  __builtin_amdgcn_global_load_lds((const __attribute__((address_space(1))) void*)g,
                                   (__attribute__((address_space(3))) void*)l,
                                   16, 0, 0);
}

// DPP sum step on the VALU pipe (avoids ds_swizzle on the shared LDS pipe).
template <int CTRL>
__device__ __forceinline__ float dppadd(float x) {
  int yi = __builtin_amdgcn_update_dpp(__float_as_int(x), __float_as_int(x),
                                       CTRL, 0xf, 0xf, false);
  return x + __int_as_float(yi);
}

// ---------------------------------------------------------------------------
// Weight transpose + fp32 -> split bf16 hi/lo: Oh/Ol[n][k] = split(W[k][n])
// ---------------------------------------------------------------------------
__global__ __launch_bounds__(256)
void transps(const float* w0, const float* w1, const float* w2,
             const float* w3, const float* w4, bf16_t* oh, bf16_t* ol)
{
  const float* Ws[5] = {w0, w1, w2, w3, w4};
  const float* W = Ws[blockIdx.z];
  const long base = (long)blockIdx.z * ((long)Cn * Cn);
  __shared__ float tile[64][65];
  const int xx = threadIdx.x & 63;
  const int y4 = threadIdx.x >> 6;
  const int bx = blockIdx.x * 64, by = blockIdx.y * 64;
#pragma unroll
  for (int i = 0; i < 16; ++i) {
    int row = i * 4 + y4;
    tile[row][xx] = W[(long)(by + row) * Cn + bx + xx];
  }
  __syncthreads();
#pragma unroll
  for (int i = 0; i < 16; ++i) {
    int row = i * 4 + y4;
    float v = tile[xx][row];
    bf16_t hi = (bf16_t)v;
    long o = base + (long)(bx + row) * Cn + by + xx;
    oh[o] = hi;
    ol[o] = (bf16_t)(v - (float)hi);
  }
}

// ---------------------------------------------------------------------------
// Split x split GEMM, 256x256 tile, BK=32, 8 waves (2M x 4N).
// 5-PHASE fine interleave per K-tile (m201 template): each phase =
//   {4-8 ds_read [+ g2l16 stage issue]} -> s_barrier -> lgkmcnt(0) +
//   sched_barrier -> setprio(1) 16-32 MFMA setprio(0) [+ mixA half] ->
//   s_barrier
// PH1: ah0-3,bh0-3 (16 MFMA ah*bh)    + stage B-hi (amode1: +A-hi)
// PH2: ah4-7       (16 MFMA ah*bh)    + stage B-lo (amode1: +A-lo)
// PH3: al0-3       (16 MFMA al*bh)    + mixA half 0 (amode0)
// PH4: al4-7 (reuse regs, 16 MFMA)    + mixA half 1 (amode0)
// PH5: bl0-3       (32 MFMA ah*bl)    + vmcnt(0) (loads issued 3-4 phases
//                                        earlier -> drain is free)
// Race bound: staging issues/writes target nb whose last reads finished in
// tile t-1 (>=2 barriers earlier); vmcnt(0)+lgkmcnt(0)+barrier per tile
// guarantee visibility before nb becomes cb. T2 slot-XOR swizzle unchanged
// (source pre-swizzle + constant read-slot XOR; conflicts measured 0).
//
// emode 0: bf16 store. 1: silu(acc)*(Zh+Zl) split store. 2: fp32. 3: split.
// ---------------------------------------------------------------------------
template <int AMODE, int EMODE>
__global__ __launch_bounds__(512)
void gemmx(const float* __restrict__ X, const float* __restrict__ tm,
           const bf16_t* __restrict__ Ah, const bf16_t* __restrict__ Al,
           const bf16_t* __restrict__ BTh, const bf16_t* __restrict__ BTl,
           void* __restrict__ Cp,
           const bf16_t* __restrict__ Zh, const bf16_t* __restrict__ Zl,
           bf16_t* __restrict__ Gh, bf16_t* __restrict__ Gl)
{
  __shared__ __align__(16) bf16_t lAh[2][256 * 32];
  __shared__ __align__(16) bf16_t lAl[2][256 * 32];
  __shared__ __align__(16) bf16_t lBh[2][256 * 32];
  __shared__ __align__(16) bf16_t lBl[2][256 * 32];

  const int tid = threadIdx.x;
  const int wv = tid >> 6;
  const int lane = tid & 63;
  const int wmw = (wv >> 2) & 1;       // M half: rows wmw*128
  const int wnw = wv & 3;              // N quarter: cols wnw*64
  const long m0 = (long)blockIdx.y * 256;
  const int n0 = blockIdx.x * 256;

  // staging: per array 256x32 elems = 2 rounds of 512 thr x 8 elems (16 B)
  const int e0 = tid * 8;
  const int e1 = 4096 + tid * 8;
  const int r0 = tid >> 2;             // 0..127 (round 1: +128)
  const int s0 = tid & 3;
  const int c0 = (s0 ^ ((r0 >> 1) & 3)) << 3;   // swizzled source column
  const long aoff0 = (m0 + r0) * Cn + c0;
  const long aoff1 = (m0 + r0 + 128) * Cn + c0;
  const long boff0 = (long)(n0 + r0) * Cn + c0;
  const long boff1 = (long)(n0 + r0 + 128) * Cn + c0;
  const bool p0ok = ((int)(m0 & (Tn - 1)) | r0) != 0;  // row r0 has prev step

  const int kg = lane >> 4;
  const int lr = lane & 15;
  const int kS = (kg ^ ((lr >> 1) & 3)) * 8;   // read-side swizzled slot
  const int aBase = (wmw * 128 + lr) * 32 + kS;
  const int bBase = (wnw * 64 + lr) * 32 + kS;

  // amode0: register mix + hi/lo split of one 128-row half -> ds_write.
  // Split into halves to cap transient VGPR (acc + ah + bh stay live).
  auto mixHalf = [&](long kc2, int dst, int half) {
    const long a = (half ? aoff1 : aoff0) + kc2;
    const int edst = half ? e1 : e0;
    float xf[8], pf[8], tf[8];
    *(f32x4*)&xf[0] = *(const f32x4*)&X[a];
    *(f32x4*)&xf[4] = *(const f32x4*)&X[a + 4];
    if (half || p0ok) {
      *(f32x4*)&pf[0] = *(const f32x4*)&X[a - Cn];
      *(f32x4*)&pf[4] = *(const f32x4*)&X[a - Cn + 4];
    } else {
#pragma unroll
      for (int q = 0; q < 8; ++q) pf[q] = 0.f;
    }
    *(f32x4*)&tf[0] = *(const f32x4*)&tm[kc2 + c0];
    *(f32x4*)&tf[4] = *(const f32x4*)&tm[kc2 + c0 + 4];
    bf16x8 hh, ll;
#pragma unroll
    for (int q = 0; q < 8; ++q) {
      float o = pf[q] + tf[q] * (xf[q] - pf[q]);
      bf16_t hi = (bf16_t)o;
      hh[q] = hi; ll[q] = (bf16_t)(o - (float)hi);
    }
    *(bf16x8*)&lAh[dst][edst] = hh;
    *(bf16x8*)&lAl[dst][edst] = ll;
  };

  // ---- prologue: stage tile 0
  if constexpr (AMODE == 0) {
    mixHalf(0, 0, 0); mixHalf(0, 0, 1);
    g2l16(BTh + boff0, &lBh[0][e0]);
    g2l16(BTh + boff1, &lBh[0][e1]);
    g2l16(BTl + boff0, &lBl[0][e0]);
    g2l16(BTl + boff1, &lBl[0][e1]);
  } else {
    g2l16(Ah + aoff0, &lAh[0][e0]);
    g2l16(Ah + aoff1, &lAh[0][e1]);
    g2l16(BTh + boff0, &lBh[0][e0]);
    g2l16(BTh + boff1, &lBh[0][e1]);
    g2l16(Al + aoff0, &lAl[0][e0]);
    g2l16(Al + aoff1, &lAl[0][e1]);
    g2l16(BTl + boff0, &lBl[0][e0]);
    g2l16(BTl + boff1, &lBl[0][e1]);
  }
  asm volatile("s_waitcnt vmcnt(0) lgkmcnt(0)" ::: "memory");
  __syncthreads();

  const int NT = Cn / 32;   // 64
  f32x4 acc[8][4] = {};
  bf16x8 ah[8], bh[4], al[4], bl[4];

  for (int t = 0; t < NT; ++t) {
    const int cb = t & 1, nb = cb ^ 1;
    const int tn = (t + 1 < NT) ? t + 1 : 0;   // wrap: dead-buffer stage
    const long kc = (long)tn * 32;

    // ---------------- PH1 : ah0-3 x bh ----------------
#pragma unroll
    for (int i = 0; i < 4; ++i)
      ah[i] = *(const bf16x8*)&lAh[cb][aBase + i * 512];
#pragma unroll
    for (int j = 0; j < 4; ++j)
      bh[j] = *(const bf16x8*)&lBh[cb][bBase + j * 512];
    if constexpr (AMODE == 0) {
      g2l16(BTh + boff0 + kc, &lBh[nb][e0]);
      g2l16(BTh + boff1 + kc, &lBh[nb][e1]);
    } else {
      g2l16(Ah + aoff0 + kc, &lAh[nb][e0]);
      g2l16(Ah + aoff1 + kc, &lAh[nb][e1]);
      g2l16(BTh + boff0 + kc, &lBh[nb][e0]);
      g2l16(BTh + boff1 + kc, &lBh[nb][e1]);
    }
    __builtin_amdgcn_s_barrier();
    asm volatile("s_waitcnt lgkmcnt(0)" ::: "memory");
    __builtin_amdgcn_sched_barrier(0);
    __builtin_amdgcn_s_setprio(1);
#pragma unroll
    for (int i = 0; i < 4; ++i)
#pragma unroll
      for (int j = 0; j < 4; ++j)
        acc[i][j] = __builtin_amdgcn_mfma_f32_16x16x32_bf16(ah[i], bh[j], acc[i][j], 0, 0, 0);
    __builtin_amdgcn_s_setprio(0);
    __builtin_amdgcn_s_barrier();

    // ---------------- PH2 : ah4-7 x bh ----------------
#pragma unroll
    for (int i = 0; i < 4; ++i)
      ah[4 + i] = *(const bf16x8*)&lAh[cb][aBase + (4 + i) * 512];
    if constexpr (AMODE == 0) {
      g2l16(BTl + boff0 + kc, &lBl[nb][e0]);
      g2l16(BTl + boff1 + kc, &lBl[nb][e1]);
    } else {
      g2l16(Al + aoff0 + kc, &lAl[nb][e0]);
      g2l16(Al + aoff1 + kc, &lAl[nb][e1]);
      g2l16(BTl + boff0 + kc, &lBl[nb][e0]);
      g2l16(BTl + boff1 + kc, &lBl[nb][e1]);
    }
    __builtin_amdgcn_s_barrier();
    asm volatile("s_waitcnt lgkmcnt(0)" ::: "memory");
    __builtin_amdgcn_sched_barrier(0);
    __builtin_amdgcn_s_setprio(1);
#pragma unroll
    for (int i = 0; i < 4; ++i)
#pragma unroll
      for (int j = 0; j < 4; ++j)
        acc[4 + i][j] = __builtin_amdgcn_mfma_f32_16x16x32_bf16(ah[4 + i], bh[j], acc[4 + i][j], 0, 0, 0);
    __builtin_amdgcn_s_setprio(0);
    __builtin_amdgcn_s_barrier();

    // ---------------- PH3 : al0-3 x bh (+ mixA half 0) ----------------
#pragma unroll
    for (int i = 0; i < 4; ++i)
      al[i] = *(const bf16x8*)&lAl[cb][aBase + i * 512];
    __builtin_amdgcn_s_barrier();
    asm volatile("s_waitcnt lgkmcnt(0)" ::: "memory");
    __builtin_amdgcn_sched_barrier(0);
    __builtin_amdgcn_s_setprio(1);
#pragma unroll
    for (int i = 0; i < 4; ++i)
#pragma unroll
      for (int j = 0; j < 4; ++j)
        acc[i][j] = __builtin_amdgcn_mfma_f32_16x16x32_bf16(al[i], bh[j], acc[i][j], 0, 0, 0);
    __builtin_amdgcn_s_setprio(0);
    if constexpr (AMODE == 0) mixHalf(kc, nb, 0);
    __builtin_amdgcn_s_barrier();

    // ---------------- PH4 : al4-7 x bh (+ mixA half 1) ----------------
#pragma unroll
    for (int i = 0; i < 4; ++i)
      al[i] = *(const bf16x8*)&lAl[cb][aBase + (4 + i) * 512];
    __builtin_amdgcn_s_barrier();
    asm volatile("s_waitcnt lgkmcnt(0)" ::: "memory");
    __builtin_amdgcn_sched_barrier(0);
    __builtin_amdgcn_s_setprio(1);
#pragma unroll
    for (int i = 0; i < 4; ++i)
#pragma unroll
      for (int j = 0; j < 4; ++j)
        acc[4 + i][j] = __builtin_amdgcn_mfma_f32_16x16x32_bf16(al[i], bh[j], acc[4 + i][j], 0, 0, 0);
    __builtin_amdgcn_s_setprio(0);
    if constexpr (AMODE == 0) mixHalf(kc, nb, 1);
    __builtin_amdgcn_s_barrier();

    // ---------------- PH5 : ah0-7 x bl (+ vmcnt drain) ----------------
#pragma unroll
    for (int j = 0; j < 4; ++j)
      bl[j] = *(const bf16x8*)&lBl[cb][bBase + j * 512];
    __builtin_amdgcn_s_barrier();
    asm volatile("s_waitcnt lgkmcnt(0)" ::: "memory");
    __builtin_amdgcn_sched_barrier(0);
    __builtin_amdgcn_s_setprio(1);
#pragma unroll
    for (int i = 0; i < 8; ++i)
#pragma unroll
      for (int j = 0; j < 4; ++j)
        acc[i][j] = __builtin_amdgcn_mfma_f32_16x16x32_bf16(ah[i], bl[j], acc[i][j], 0, 0, 0);
    __builtin_amdgcn_s_setprio(0);
    asm volatile("s_waitcnt vmcnt(0)" ::: "memory");   // staged 3-4 phases ago
    __builtin_amdgcn_sched_barrier(0);
    __builtin_amdgcn_s_barrier();
  }

  // C/D layout: col = lane&15, row = (lane>>4)*4 + reg   [m89-verified]
  const int qr = lane >> 4;
  const int cnn = lane & 15;
#pragma unroll
  for (int i = 0; i < 8; ++i) {
#pragma unroll
    for (int j = 0; j < 4; ++j) {
#pragma unroll
      for (int rg = 0; rg < 4; ++rg) {
        long row = m0 + wmw * 128 + i * 16 + qr * 4 + rg;
        int col = n0 + wnw * 64 + j * 16 + cnn;
        long off = row * Cn + col;
        float vv = acc[i][j][rg];
        if constexpr (EMODE == 0) {
          ((bf16_t*)Cp)[off] = (bf16_t)vv;
        } else if constexpr (EMODE == 1) {
          float z = (float)Zh[off] + (float)Zl[off];
          float zg = vv / (1.f + __expf(-vv)) * z;
          bf16_t hi = (bf16_t)zg;
          Gh[off] = hi;
          Gl[off] = (bf16_t)(zg - (float)hi);
        } else if constexpr (EMODE == 2) {
          ((float*)Cp)[off] = vv;
        } else {   // 3: split store
          bf16_t hi = (bf16_t)vv;
          Gh[off] = hi;
          Gl[off] = (bf16_t)(vv - (float)hi);
        }
      }
    }
  }
}

// ---------------------------------------------------------------------------
// wkv5 recurrence + fused /8 + GroupNorm(64, one-pass) + ln scale/shift.
// One block per (b,h), 512 threads. DPP reductions on the VALU pipe
// (round-6 verified: 650 -> 570 us, VALUBusy 63). Structure unchanged.
// ---------------------------------------------------------------------------
__global__ __launch_bounds__(512)
void wkv5(const bf16_t* Rh, const bf16_t* __restrict__ Rl,
          const bf16_t* Km, const bf16_t* __restrict__ Vm,
          const float* __restrict__ decay, const float* __restrict__ faaaa,
          const float* __restrict__ lw, const float* __restrict__ lb,
          bf16_t* Zh, bf16_t* Zl)
{
  const int bh = blockIdx.x;
  const int b = bh >> 5;          // H = 32
  const int h = bh & 31;
  const int tid = threadIdx.x;
  const int j = tid >> 3;         // value column 0..63
  const int ic = tid & 7;         // i-slice 0..7
  const int i0 = ic * 8;

  float w[8], u[8], S[8];
#pragma unroll
  for (int q = 0; q < 8; ++q) {
    w[q] = expf(-expf(decay[h * 64 + i0 + q]));
    u[q] = faaaa[h * 64 + i0 + q];
    S[q] = 0.f;
  }

  __shared__ __align__(16) float sR[2][CT * 64];   // 32 KB
  __shared__ __align__(16) float sK[2][CT * 64];   // 32 KB
  __shared__ __align__(16) float sV[2][CT * 64];   // 32 KB
  __shared__ __align__(16) float sY[CT * 64];      // 16 KB
  __shared__ float sA[2][CT];                      // 0.5 KB  (ap per t)

  const int e = tid * 8;          // 512*8 = 4096 = CT*64
  const int tl = e >> 6;          // = tid>>3 : timestep within chunk
  const int cc = e & 63;          // = (tid&7)*8 : channel slice (== i0)
  const long gbase = (long)b * Tn * Cn + h * 64 + cc;

  const int wv = tid >> 6;        // wave 0..7
  const int ln = tid & 63;
  const float lwv = lw[h * 64 + ln];
  const float lbv = lb[h * 64 + ln];

  bf16x8 prh, prl, pk, pv;
  auto issue = [&](int cch) {
    const long g = gbase + (long)(cch * CT + tl) * Cn;
    prh = *(const bf16x8*)&Rh[g];
    prl = *(const bf16x8*)&Rl[g];
    pk  = *(const bf16x8*)&Km[g];
    pv  = *(const bf16x8*)&Vm[g];
  };
  auto commit = [&](int bufA) {
    float apv = 0.f;
#pragma unroll
    for (int q = 0; q < 8; ++q) {
      float rf = (float)prh[q] + (float)prl[q];
      float kf = (float)pk[q];
      sR[bufA][e + q] = rf;
      sK[bufA][e + q] = kf;
      sV[bufA][e + q] = (float)pv[q];
      apv += (rf * u[q]) * kf;    // thread's u-slice matches cc == i0
    }
    apv = dppadd<0xB1>(apv);      // xor1  (VALU)
    apv = dppadd<0x4E>(apv);      // xor2  (VALU)
    apv = dppadd<0x141>(apv);     // 8-group via row_half_mirror (VALU)
    if (ic == 0) sA[bufA][tl] = apv;
  };

  issue(0); commit(0);
  __syncthreads();
  issue(1);

  const int NC = Tn / CT;   // 32
  for (int cch = 0; cch < NC; ++cch) {
    const int buf = cch & 1;
#pragma unroll 4
    for (int t = 0; t < CT; ++t) {
      float rr[8], kk[8];
      *(f32x4*)&rr[0] = *(const f32x4*)&sR[buf][t * 64 + i0];
      *(f32x4*)&rr[4] = *(const f32x4*)&sR[buf][t * 64 + i0 + 4];
      *(f32x4*)&kk[0] = *(const f32x4*)&sK[buf][t * 64 + i0];
      *(f32x4*)&kk[4] = *(const f32x4*)&sK[buf][t * 64 + i0 + 4];
      float vj = sV[buf][t * 64 + j];
      float yp = 0.f;
#pragma unroll
      for (int q = 0; q < 8; ++q) {
        yp += rr[q] * S[q];
        S[q] = w[q] * S[q] + kk[q] * vj;
      }
      yp = dppadd<0xB1>(yp);      // xor1  (VALU)
      yp = dppadd<0x4E>(yp);      // xor2  (VALU)
      yp = dppadd<0x141>(yp);     // 8-group (VALU)
      if (ic == 0) sY[t * 64 + j] = (yp + sA[buf][t] * vj) * 0.125f;
    }
    if (cch + 1 < NC) commit((cch + 1) & 1);
    __syncthreads();
    if (cch + 2 < NC) issue(cch + 2);

    const long zrow0 = ((long)b * Tn + (long)cch * CT) * Cn + h * 64 + ln;
#pragma unroll
    for (int q = 0; q < 8; ++q) {
      const int t = wv * 8 + q;
      float val = sY[t * 64 + ln];
      float s = val, s2 = val * val;
      s = dppadd<0xB1>(s);   s2 = dppadd<0xB1>(s2);    // xor1
      s = dppadd<0x4E>(s);   s2 = dppadd<0x4E>(s2);    // xor2
      s = dppadd<0x141>(s);  s2 = dppadd<0x141>(s2);   // 8-group
      s = dppadd<0x140>(s);  s2 = dppadd<0x140>(s2);   // 16-group (mirror)
      s  += __shfl_xor(s, 16);  s2 += __shfl_xor(s2, 16);
      s  += __shfl_xor(s, 32);  s2 += __shfl_xor(s2, 32);
      float mu = s * (1.f / 64.f);
      float var = fmaxf(s2 * (1.f / 64.f) - mu * mu, 0.f);
      float rs = rsqrtf(var + 1e-5f);
      float zv = (val - mu) * rs * lwv + lbv;
      bf16_t zh = (bf16_t)zv;
      Zh[zrow0 + (long)t * Cn] = zh;
      Zl[zrow0 + (long)t * Cn] = (bf16_t)(zv - (float)zh);
    }
    __syncthreads();
  }
}

// ---------------------------------------------------------------------------
extern "C" void kernel_launch(void* const* d_in, const int* in_sizes, int n_in,
                              void* d_out, int out_size, void* d_ws, size_t ws_size,
                              hipStream_t stream)
{
  const float* x    = (const float*)d_in[0];
  const float* tmk  = (const float*)d_in[1];
  const float* tmv  = (const float*)d_in[2];
  const float* tmr  = (const float*)d_in[3];
  const float* tmg  = (const float*)d_in[4];
  const float* tdec = (const float*)d_in[5];
  const float* tfaa = (const float*)d_in[6];
  const float* Wr   = (const float*)d_in[7];
  const float* Wk   = (const float*)d_in[8];
  const float* Wv   = (const float*)d_in[9];
  const float* Wg   = (const float*)d_in[10];
  const float* Wo   = (const float*)d_in[11];
  const float* lnw  = (const float*)d_in[12];
  const float* lnb  = (const float*)d_in[13];

  // ws layout (218.1 MB):
  //   [0, 41.9MB)      wTh : 5 transposed weight hi
  //   [41.9, 83.9MB)   wTl : 5 transposed weight lo
  //   sl0: v,    then zg_hi
  //   sl1: r_lo, then zg_lo
  // d_out (134 MB fp32 = 2 bf16 slots):
  //   d0a: r_hi, then z_hi;  d0b: k, then z_lo;  finally fp32 out.
  char* ws = (char*)d_ws;
  const long WSZ = (long)Cn * Cn;
  const long SZB = SZ * 2;                  // 67,108,864 B per bf16 slot
  bf16_t* wTh = (bf16_t*)ws;
  bf16_t* wTl = (bf16_t*)(ws + 5 * WSZ * 2);
  bf16_t* sl0 = (bf16_t*)(ws + 10 * WSZ * 2);
  bf16_t* sl1 = (bf16_t*)(ws + 10 * WSZ * 2 + SZB);
  bf16_t* d0a = (bf16_t*)d_out;
  bf16_t* d0b = (bf16_t*)d_out + SZ;

  const dim3 gGrid(8, 64, 1);   // 256x256 tiles over [16384, 2048]

  transps<<<dim3(32, 32, 5), 256, 0, stream>>>(Wr, Wk, Wv, Wg, Wo, wTh, wTl);

  // r = mix(x,tmr) @ Wr, split -> hi d0a, lo sl1
  gemmx<0, 3><<<gGrid, 512, 0, stream>>>(x, tmr, nullptr, nullptr,
                                         wTh + 0 * WSZ, wTl + 0 * WSZ, nullptr,
                                         nullptr, nullptr, d0a, sl1);
  // k = mix(x,tmk) @ Wk -> bf16 d0b
  gemmx<0, 0><<<gGrid, 512, 0, stream>>>(x, tmk, nullptr, nullptr,
                                         wTh + 1 * WSZ, wTl + 1 * WSZ, d0b,
                                         nullptr, nullptr, nullptr, nullptr);
  // v = mix(x,tmv) @ Wv -> bf16 sl0
  gemmx<0, 0><<<gGrid, 512, 0, stream>>>(x, tmv, nullptr, nullptr,
                                         wTh + 2 * WSZ, wTl + 2 * WSZ, sl0,
                                         nullptr, nullptr, nullptr, nullptr);

  // wkv5 + /8 + groupnorm -> z split: hi over d0a (r_hi), lo over d0b (k)
  wkv5<<<256, 512, 0, stream>>>(d0a, sl1, d0b, sl0, tdec, tfaa, lnw, lnb,
                                d0a, d0b);

  // zg = silu(mix(x,tmg) @ Wg) * (z_hi+z_lo), split -> hi sl0, lo sl1
  gemmx<0, 1><<<gGrid, 512, 0, stream>>>(x, tmg, nullptr, nullptr,
                                         wTh + 3 * WSZ, wTl + 3 * WSZ, nullptr,
                                         d0a, d0b, sl0, sl1);

  // out = (zg_hi+zg_lo) @ Wo -> fp32 d_out
  gemmx<1, 2><<<gGrid, 512, 0, stream>>>(nullptr, nullptr, sl0, sl1,
                                         wTh + 4 * WSZ, wTl + 4 * WSZ, d_out,
                                         nullptr, nullptr, nullptr, nullptr);
}